// Round 1
// baseline (396.779 us; speedup 1.0000x reference)
//
#include <hip/hip_runtime.h>

// CRF loss (B=1024, T=512, L=62, K=64) for MI355X / gfx950.
// Kernel 1: forward recursion, one 64-lane wave per batch (lane j = state j).
//   log-domain recursion done as linear matvec against E = exp(trans),
//   with uniform per-step renormalization (M = alpha[lane0]) into c_total.
// Kernel 2: gold path score (emissions + transition path), one wave per batch.
// Kernel 3: final reduction -> out[0] = sum_b(ln2 * fwd_scaled_b - gold_b).

#define SMALLF   (-1000.0f)
#define LOG2E_F  1.4426950408889634f
#define LN2_D    0.6931471805599453

#if defined(__has_builtin)
#if __has_builtin(__builtin_amdgcn_exp2f)
#define EXP2F(x) __builtin_amdgcn_exp2f(x)
#else
#define EXP2F(x) exp2f(x)
#endif
#if __has_builtin(__builtin_amdgcn_logf)
#define LOG2F(x) __builtin_amdgcn_logf(x)
#else
#define LOG2F(x) log2f(x)
#endif
#else
#define EXP2F(x) exp2f(x)
#define LOG2F(x) log2f(x)
#endif

__device__ __forceinline__ float bcast_lane(float v, int lane) {
    return __uint_as_float(__builtin_amdgcn_readlane(__float_as_uint(v), lane));
}
__device__ __forceinline__ float bcast_first(float v) {
    return __uint_as_float(__builtin_amdgcn_readfirstlane(__float_as_uint(v)));
}

// ---------------- forward kernel ----------------
__global__ __launch_bounds__(64) void crf_forward_kernel(
    const float* __restrict__ pred,     // (B,T,L)
    const int*   __restrict__ seq_len,  // (B,)
    const float* __restrict__ trans,    // (64,64)
    float*       __restrict__ fwd_out,  // (B,) scaled (base-2) logZ
    int T, int L)
{
    const int b    = blockIdx.x;
    const int lane = threadIdx.x;

    // E[i] = exp(trans[i][lane]); rows 62,63 are -10000 -> E == 0 exactly,
    // which reproduces the reference's exp(-10000-ish)->0 underflow.
    float E[64];
#pragma unroll
    for (int i = 0; i < 64; ++i)
        E[i] = EXP2F(trans[i * 64 + lane] * LOG2E_F);

    float se = 0.f;
#pragma unroll
    for (int i = 0; i < 62; ++i) se += E[i];
    const float Slog = LOG2F(se);   // log2(sum_{i<62} e^{trans[i][lane]})

    const int slen  = seq_len[b];
    const int t_end = slen + 1;     // observations index of final step (>=2)
    const float* prow = pred + (size_t)b * T * L;

    // ---- step t=1 analytically:
    // alpha1[j] = obs1[j] + SMALL + ln(sum_{i<62} e^{trans[i][j]})   (base-2 scaled)
    float pv1 = (lane < L) ? prow[lane] : 0.f;
    float o1  = (lane < L) ? pv1 : SMALLF;
    float alpha   = (o1 + SMALLF) * LOG2E_F + Slog;
    float c_total = 0.f;

    // prefetch ring for t = 2..5 (pred row t-1)
    float ring[4];
#pragma unroll
    for (int u = 0; u < 4; ++u) {
        int rr = (1 + u) < T ? (1 + u) : (T - 1);
        ring[u] = (lane < L) ? prow[(size_t)rr * L + lane] : 0.f;
    }

    for (int t0 = 2; t0 <= t_end; t0 += 4) {
#pragma unroll
        for (int u = 0; u < 4; ++u) {
            const int t = t0 + u;
            if (t > t_end) break;
            const float pv = ring[u];
            {   // prefetch row for step t+4 (clamped; harmless if unused)
                int rr = (t + 3) < T ? (t + 3) : (T - 1);
                ring[u] = (lane < L) ? prow[(size_t)rr * L + lane] : 0.f;
            }
            // observation for step t (unscaled, per reference)
            float o;
            if (t <= T) o = (lane < L) ? pv : SMALLF;
            else        o = (lane < L) ? 0.f : SMALLF;      // r_pad row
            if (t == t_end)                                  // e_s at seq_len+1
                o += (lane < L) ? SMALLF : ((lane == L) ? 0.f : 1000.f);
            const float obs_s = o * LOG2E_F;

            // uniform renormalization: lane 0 is always a live label here
            const float M = bcast_first(alpha);
            c_total += M;
            const float p = EXP2F(alpha - M);   // per-lane forward mass

            // ssum[j] = sum_{i<62} p_i * E[i][j]   (i=62,63 have E==0)
            float a0 = 0.f, a1 = 0.f, a2 = 0.f, a3 = 0.f;
#pragma unroll
            for (int i = 0; i < 60; i += 4) {
                a0 = fmaf(bcast_lane(p, i + 0), E[i + 0], a0);
                a1 = fmaf(bcast_lane(p, i + 1), E[i + 1], a1);
                a2 = fmaf(bcast_lane(p, i + 2), E[i + 2], a2);
                a3 = fmaf(bcast_lane(p, i + 3), E[i + 3], a3);
            }
            a0 = fmaf(bcast_lane(p, 60), E[60], a0);
            a1 = fmaf(bcast_lane(p, 61), E[61], a1);
            const float ssum = (a0 + a1) + (a2 + a3);

            alpha = obs_s + LOG2F(ssum);
        }
    }

    // final logsumexp over the 64 states (exact, one-time)
    float m = alpha;
#pragma unroll
    for (int k = 32; k >= 1; k >>= 1)
        m = fmaxf(m, __shfl_xor(m, k, 64));
    float pe = EXP2F(alpha - m);
#pragma unroll
    for (int k = 32; k >= 1; k >>= 1)
        pe += __shfl_xor(pe, k, 64);
    if (lane == 0)
        fwd_out[b] = c_total + m + LOG2F(pe);   // base-2 scaled logZ
}

// ---------------- gold-score kernel ----------------
__global__ __launch_bounds__(64) void crf_gold_kernel(
    const float* __restrict__ pred,     // (B,T,L)
    const int*   __restrict__ ref,      // (B,T)
    const int*   __restrict__ seq_len,  // (B,)
    const float* __restrict__ trans,    // (64,64)
    float*       __restrict__ gold_out, // (B,) unscaled
    int T, int L)
{
    const int b    = blockIdx.x;
    const int lane = threadIdx.x;
    const int slen = seq_len[b];
    const int*   rrow = ref  + (size_t)b * T;
    const float* prow = pred + (size_t)b * T * L;

    float acc = 0.f;
    for (int t = lane; t < slen; t += 64) {
        const int c = rrow[t];
        acc += prow[(size_t)t * L + c];               // gold emission
        if (t >= 1)
            acc += trans[rrow[t - 1] * 64 + c];       // internal transition
    }
    if (lane == 0)
        acc += trans[62 * 64 + rrow[0]]               // start -> ref[0]
             + trans[rrow[slen - 1] * 64 + 63];       // ref[slen-1] -> end
#pragma unroll
    for (int k = 32; k >= 1; k >>= 1)
        acc += __shfl_xor(acc, k, 64);
    if (lane == 0) gold_out[b] = acc;
}

// ---------------- reduction kernel ----------------
__global__ __launch_bounds__(256) void crf_reduce_kernel(
    const float* __restrict__ fwd,   // (B,) base-2 scaled
    const float* __restrict__ gold,  // (B,)
    float*       __restrict__ out,
    int B)
{
    __shared__ double sm[256];
    const int tid = threadIdx.x;
    double s = 0.0;
    for (int i = tid; i < B; i += 256)
        s += (double)fwd[i] * LN2_D - (double)gold[i];
    sm[tid] = s;
    __syncthreads();
    for (int k = 128; k >= 1; k >>= 1) {
        if (tid < k) sm[tid] += sm[tid + k];
        __syncthreads();
    }
    if (tid == 0) out[0] = (float)sm[0];
}

extern "C" void kernel_launch(void* const* d_in, const int* in_sizes, int n_in,
                              void* d_out, int out_size, void* d_ws, size_t ws_size,
                              hipStream_t stream) {
    const float* pred  = (const float*)d_in[0];
    const int*   ref   = (const int*)  d_in[1];
    const int*   slen  = (const int*)  d_in[2];
    const float* trans = (const float*)d_in[3];

    const int B = in_sizes[2];                 // 1024
    const int T = in_sizes[1] / B;             // 512
    const int L = in_sizes[0] / (in_sizes[1]); // 62

    float* fwd  = (float*)d_ws;
    float* gold = fwd + B;

    crf_forward_kernel<<<B, 64, 0, stream>>>(pred, slen, trans, fwd, T, L);
    crf_gold_kernel  <<<B, 64, 0, stream>>>(pred, ref, slen, trans, gold, T, L);
    crf_reduce_kernel<<<1, 256, 0, stream>>>(fwd, gold, (float*)d_out, B);
}